// Round 1
// baseline (1051.221 us; speedup 1.0000x reference)
//
#include <hip/hip_runtime.h>

#define B_ 32
#define K_ 10
#define T_ 128
#define L_ 128
#define D_ 1024
#define NT_ 32
#define S_ (K_*L_)     // 1280
#define NCH_ 10        // S chunks for argmin GEMM
#define SCH_ 128
#define BIGF 1e30f

// ---------------- K1: test_mean = mean over K ----------------
__global__ __launch_bounds__(256) void k_mean(const float* __restrict__ tr, float* __restrict__ tm){
  int idx = blockIdx.x*256 + threadIdx.x;       // over B*T*(D/4)
  int d4 = idx & 255;                           // D/4 = 256
  int t  = (idx >> 8) & 127;
  int b  = idx >> 15;
  const float4* p = (const float4*)tr;
  float4 a = make_float4(0.f,0.f,0.f,0.f);
  #pragma unroll
  for(int k=0;k<K_;k++){
    float4 v = p[((size_t)(b*K_+k)*T_ + t)*(D_/4) + d4];
    a.x+=v.x; a.y+=v.y; a.z+=v.z; a.w+=v.w;
  }
  const float sc = 1.f/(float)K_;
  a.x*=sc; a.y*=sc; a.z*=sc; a.w*=sc;
  ((float4*)tm)[((size_t)b*T_ + t)*(D_/4) + d4] = a;
}

// ---------------- K2: support row norms + labels (one wave per row) ----------------
__global__ __launch_bounds__(256) void k_norm_label(const float* __restrict__ sup, const float* __restrict__ tgt,
                                                    float* __restrict__ norms, int* __restrict__ labels){
  int lane = threadIdx.x & 63;
  int r = blockIdx.x*4 + (threadIdx.x >> 6);    // r < B*S
  const float4* p = (const float4*)sup + (size_t)r*(D_/4);
  float s = 0.f;
  #pragma unroll
  for(int i=0;i<4;i++){
    float4 v = p[lane + 64*i];
    s += v.x*v.x + v.y*v.y + v.z*v.z + v.w*v.w;
  }
  #pragma unroll
  for(int o=32;o>0;o>>=1) s += __shfl_down(s, o, 64);
  float tv = (lane < NT_) ? tgt[(size_t)r*NT_ + lane] : 0.f;
  unsigned long long m = __ballot(tv > 0.5f);
  if(lane == 0){ norms[r] = s; labels[r] = (int)__ffsll((long long)m) - 1; }
}

// ---------------- K3: prototypes via LDS ds_add_f32 scatter ----------------
// grid: (b * 8 d-chunks of 128), 256 threads (two s-parity halves share one LDS acc via atomics)
__global__ __launch_bounds__(256) void k_proto(const float* __restrict__ sup, const int* __restrict__ labels,
                                               float* __restrict__ proto){
  __shared__ float acc[NT_][128];
  __shared__ int lbl[S_];
  __shared__ int cnt[NT_];
  int b = blockIdx.x >> 3;
  int dc = blockIdx.x & 7;
  int tid = threadIdx.x;
  for(int i=tid;i<NT_*128;i+=256) (&acc[0][0])[i] = 0.f;
  if(tid < NT_) cnt[tid] = 0;
  for(int s=tid;s<S_;s+=256) lbl[s] = labels[b*S_ + s];
  __syncthreads();
  for(int s=tid;s<S_;s+=256) atomicAdd(&cnt[lbl[s]], 1);
  int ph = tid >> 7, c = tid & 127;
  const float* base = sup + (size_t)b*S_*D_ + dc*128 + c;
  #pragma unroll 8
  for(int s=ph;s<S_;s+=2){
    atomicAdd(&acc[lbl[s]][c], base[(size_t)s*D_]);   // ds_add_f32, no RMW dep chain
  }
  __syncthreads();
  if(tid < 128){
    #pragma unroll
    for(int n=0;n<NT_;n++){
      float v = acc[n][c] / ((float)cnt[n] + 1e-4f);
      proto[((size_t)b*NT_ + n)*D_ + dc*128 + c] = v;
    }
  }
}

// ---------------- K4: fp32 tiled GEMM (-2*t.s + ||s||^2) + per-chunk argmin ----------------
// grid: b * NCH_; tile 128(T) x 128(S) x D, 256 threads, 8x8 micro-tile
__global__ __launch_bounds__(256) void k_gemm_argmin(const float* __restrict__ tm, const float* __restrict__ sup,
        const float* __restrict__ norms, float* __restrict__ pval, int* __restrict__ pidx){
  __shared__ float As[16][132];
  __shared__ float Bs[16][132];
  __shared__ float rv[T_][16];
  __shared__ int   ri[T_][16];
  int b = blockIdx.x / NCH_;
  int ch = blockIdx.x % NCH_;
  int sbase = ch * SCH_;
  int tid = threadIdx.x;
  int tx = tid & 15, ty = tid >> 4;
  int lr = tid >> 2;             // 0..63 row for staging
  int k4 = (tid & 3) << 2;       // k offset within 16-tile
  const float* tmb  = tm  + (size_t)b*T_*D_;
  const float* supb = sup + ((size_t)b*S_ + sbase)*D_;
  float acc[8][8];
  #pragma unroll
  for(int i=0;i<8;i++)
    #pragma unroll
    for(int j=0;j<8;j++) acc[i][j]=0.f;

  for(int kk=0;kk<D_;kk+=16){
    float4 a0 = *(const float4*)(tmb  + (size_t)lr*D_      + kk + k4);
    float4 a1 = *(const float4*)(tmb  + (size_t)(lr+64)*D_ + kk + k4);
    float4 b0 = *(const float4*)(supb + (size_t)lr*D_      + kk + k4);
    float4 b1 = *(const float4*)(supb + (size_t)(lr+64)*D_ + kk + k4);
    __syncthreads();
    As[k4+0][lr]=a0.x; As[k4+1][lr]=a0.y; As[k4+2][lr]=a0.z; As[k4+3][lr]=a0.w;
    As[k4+0][lr+64]=a1.x; As[k4+1][lr+64]=a1.y; As[k4+2][lr+64]=a1.z; As[k4+3][lr+64]=a1.w;
    Bs[k4+0][lr]=b0.x; Bs[k4+1][lr]=b0.y; Bs[k4+2][lr]=b0.z; Bs[k4+3][lr]=b0.w;
    Bs[k4+0][lr+64]=b1.x; Bs[k4+1][lr+64]=b1.y; Bs[k4+2][lr+64]=b1.z; Bs[k4+3][lr+64]=b1.w;
    __syncthreads();
    #pragma unroll
    for(int k=0;k<16;k++){
      float4 av0 = *(const float4*)&As[k][ty*8];
      float4 av1 = *(const float4*)&As[k][ty*8+4];
      float4 bv0 = *(const float4*)&Bs[k][tx*8];
      float4 bv1 = *(const float4*)&Bs[k][tx*8+4];
      float a_[8] = {av0.x,av0.y,av0.z,av0.w,av1.x,av1.y,av1.z,av1.w};
      float b_[8] = {bv0.x,bv0.y,bv0.z,bv0.w,bv1.x,bv1.y,bv1.z,bv1.w};
      #pragma unroll
      for(int i=0;i<8;i++)
        #pragma unroll
        for(int j=0;j<8;j++) acc[i][j] += a_[i]*b_[j];
    }
  }
  // epilogue: score = norm[s] - 2*dot; first-min tie-break (ascending s everywhere, strict <)
  float nrm[8];
  #pragma unroll
  for(int j=0;j<8;j++) nrm[j] = norms[(size_t)b*S_ + sbase + tx*8 + j];
  #pragma unroll
  for(int i=0;i<8;i++){
    float bv = BIGF; int bj = 0;
    #pragma unroll
    for(int j=0;j<8;j++){
      float v = nrm[j] - 2.f*acc[i][j];
      if(v < bv){ bv = v; bj = j; }
    }
    rv[ty*8+i][tx] = bv;
    ri[ty*8+i][tx] = sbase + tx*8 + bj;
  }
  __syncthreads();
  if(tid < T_){
    float bv = BIGF; int bi = 0;
    #pragma unroll
    for(int x=0;x<16;x++){
      float v = rv[tid][x];
      if(v < bv){ bv = v; bi = ri[tid][x]; }
    }
    pval[(size_t)(b*T_ + tid)*NCH_ + ch] = bv;
    pidx[(size_t)(b*T_ + tid)*NCH_ + ch] = bi;
  }
}

// ---------------- K5: chunk-reduce argmin + onehot + 0.5 * tm . proto^T ----------------
// grid: B_, 256 threads. thread owns n = tid&31, t-group tg = tid>>5 (t = iter*8+tg)
__global__ __launch_bounds__(256) void k_final(const float* __restrict__ tm, const float* __restrict__ pval,
        const int* __restrict__ pidx, const int* __restrict__ labels, const float* __restrict__ proto,
        float* __restrict__ out0){
  __shared__ float pl[256][33];   // proto chunk transposed [d][n], pad 33 -> conflict-free
  __shared__ float tl[8][260];    // 8 test rows x 256 d
  __shared__ int lbl_t[T_];
  int b = blockIdx.x;
  int tid = threadIdx.x;
  if(tid < T_){
    float bv = BIGF; int bi = 0;
    #pragma unroll
    for(int c=0;c<NCH_;c++){
      float v = pval[(size_t)(b*T_ + tid)*NCH_ + c];
      if(v < bv){ bv = v; bi = pidx[(size_t)(b*T_ + tid)*NCH_ + c]; }
    }
    lbl_t[tid] = labels[b*S_ + bi];
  }
  float accv[16];
  #pragma unroll
  for(int i=0;i<16;i++) accv[i]=0.f;
  int n = tid & 31, tg = tid >> 5;
  for(int chd=0; chd<4; chd++){
    __syncthreads();
    for(int idx=tid; idx<NT_*256; idx+=256){
      int nn = idx >> 8, d = idx & 255;
      pl[d][nn] = proto[((size_t)b*NT_ + nn)*D_ + chd*256 + d];
    }
    __syncthreads();
    for(int iter=0; iter<16; iter++){
      __syncthreads();
      for(int idx=tid; idx<8*256; idx+=256){
        int r = idx >> 8, d = idx & 255;
        tl[r][d] = tm[((size_t)b*T_ + iter*8 + r)*D_ + chd*256 + d];
      }
      __syncthreads();
      float a = accv[iter];
      #pragma unroll 8
      for(int d=0; d<256; d++) a += tl[tg][d] * pl[d][n];
      accv[iter] = a;
    }
  }
  __syncthreads();
  #pragma unroll
  for(int iter=0; iter<16; iter++){
    int t = iter*8 + tg;
    float v = 0.5f*accv[iter] + ((lbl_t[t]==n) ? 1.f : 0.f);
    out0[((size_t)b*T_ + t)*NT_ + n] = v;
  }
}

extern "C" void kernel_launch(void* const* d_in, const int* in_sizes, int n_in,
                              void* d_out, int out_size, void* d_ws, size_t ws_size,
                              hipStream_t stream){
  const float* tr  = (const float*)d_in[0];   // test_reps    (B,K,T,D)
  const float* sup = (const float*)d_in[1];   // support_reps (B,K,L,D)
  const float* tgt = (const float*)d_in[4];   // support_targets (B,K,L,NT) one-hot
  float* out0  = (float*)d_out;                       // (B,T,NT)
  float* proto = out0 + (size_t)B_*T_*NT_;            // (B,NT,D) = output 1

  float* tm    = (float*)d_ws;                        // B*T*D
  float* norms = tm + (size_t)B_*T_*D_;               // B*S
  int*   labels= (int*)(norms + (size_t)B_*S_);       // B*S
  float* pval  = (float*)(labels + (size_t)B_*S_);    // B*T*NCH_
  int*   pidx  = (int*)(pval + (size_t)B_*T_*NCH_);   // B*T*NCH_

  k_mean<<<(B_*T_*(D_/4))/256, 256, 0, stream>>>(tr, tm);
  k_norm_label<<<(B_*S_)/4, 256, 0, stream>>>(sup, tgt, norms, labels);
  k_proto<<<B_*8, 256, 0, stream>>>(sup, labels, proto);
  k_gemm_argmin<<<B_*NCH_, 256, 0, stream>>>(tm, sup, norms, pval, pidx);
  k_final<<<B_, 256, 0, stream>>>(tm, pval, pidx, labels, proto, out0);
}

// Round 2
// 722.182 us; speedup vs baseline: 1.4556x; 1.4556x over previous
//
#include <hip/hip_runtime.h>

#define B_ 32
#define K_ 10
#define T_ 128
#define L_ 128
#define D_ 1024
#define NT_ 32
#define S_ (K_*L_)     // 1280
#define NCH_ 10        // S chunks of 128
#define SCH_ 128
#define PVW_ (NCH_*2)  // pval entries per row (chunk x n-half)
#define BIGF 1e30f

typedef __attribute__((ext_vector_type(8))) short short8;
typedef __attribute__((ext_vector_type(4))) float f32x4;

__device__ __forceinline__ unsigned short bf16rn(float f){
  unsigned int u = __float_as_uint(f);
  u = (u + 0x7FFFu + ((u >> 16) & 1u)) >> 16;
  return (unsigned short)u;
}
__device__ __forceinline__ float bf2f(unsigned short h){
  return __uint_as_float(((unsigned int)h) << 16);
}

// ---------------- K1: test_mean = mean over K ----------------
__global__ __launch_bounds__(256) void k_mean(const float* __restrict__ tr, float* __restrict__ tm){
  int idx = blockIdx.x*256 + threadIdx.x;       // over B*T*(D/4)
  int d4 = idx & 255;
  int t  = (idx >> 8) & 127;
  int b  = idx >> 15;
  const float4* p = (const float4*)tr;
  float4 a = make_float4(0.f,0.f,0.f,0.f);
  #pragma unroll
  for(int k=0;k<K_;k++){
    float4 v = p[((size_t)(b*K_+k)*T_ + t)*(D_/4) + d4];
    a.x+=v.x; a.y+=v.y; a.z+=v.z; a.w+=v.w;
  }
  const float sc = 1.f/(float)K_;
  a.x*=sc; a.y*=sc; a.z*=sc; a.w*=sc;
  ((float4*)tm)[((size_t)b*T_ + t)*(D_/4) + d4] = a;
}

// ---------------- K2: labels from one-hot targets ----------------
__global__ __launch_bounds__(256) void k_label(const float* __restrict__ tgt, int* __restrict__ labels){
  int r = blockIdx.x*256 + threadIdx.x;         // r < B*S
  const float4* p = (const float4*)tgt + (size_t)r*8;
  int lbl = 0;
  #pragma unroll
  for(int j=0;j<8;j++){
    float4 v = p[j];
    if(v.x>0.5f) lbl=j*4+0;
    if(v.y>0.5f) lbl=j*4+1;
    if(v.z>0.5f) lbl=j*4+2;
    if(v.w>0.5f) lbl=j*4+3;
  }
  labels[r] = lbl;
}

// ---------------- K3: prototypes via LDS ds_add_f32 scatter ----------------
__global__ __launch_bounds__(256) void k_proto(const float* __restrict__ sup, const int* __restrict__ labels,
                                               float* __restrict__ proto){
  __shared__ float acc[NT_][128];
  __shared__ int lbl[S_];
  __shared__ int cnt[NT_];
  int b = blockIdx.x >> 3;
  int dc = blockIdx.x & 7;
  int tid = threadIdx.x;
  for(int i=tid;i<NT_*128;i+=256) (&acc[0][0])[i] = 0.f;
  if(tid < NT_) cnt[tid] = 0;
  for(int s=tid;s<S_;s+=256) lbl[s] = labels[b*S_ + s];
  __syncthreads();
  for(int s=tid;s<S_;s+=256) atomicAdd(&cnt[lbl[s]], 1);
  int ph = tid >> 7, c = tid & 127;
  const float* base = sup + (size_t)b*S_*D_ + dc*128 + c;
  #pragma unroll 8
  for(int s=ph;s<S_;s+=2){
    atomicAdd(&acc[lbl[s]][c], base[(size_t)s*D_]);
  }
  __syncthreads();
  if(tid < 128){
    #pragma unroll
    for(int n=0;n<NT_;n++){
      float v = acc[n][c] / ((float)cnt[n] + 1e-4f);
      proto[((size_t)b*NT_ + n)*D_ + dc*128 + c] = v;
    }
  }
}

// ---------------- K4: split-bf16 MFMA GEMM (-2*t.s + ||s||^2) + per-chunk argmin ----------------
// grid b*NCH_; 256 thr = 4 waves in 2x2; block tile 128(T) x 128(S), BK=32 fp32 staged as bf16 hi/lo.
// LDS frag-major: seg(mt,p) = 1KB holding the exact 64-lane x 16B fragment -> conflict-free b128.
__global__ __launch_bounds__(256) void k_gemm_argmin(const float* __restrict__ tm, const float* __restrict__ sup,
        float* __restrict__ pval, int* __restrict__ pidx){
  __shared__ __align__(16) short ldsA[16*512];   // 8 mt x 2 planes x 512 shorts (1KB segs)
  __shared__ __align__(16) short ldsB[16*512];
  __shared__ float normB[128];

  int b = blockIdx.x / NCH_;
  int ch = blockIdx.x % NCH_;
  int sbase = ch * SCH_;
  int tid = threadIdx.x;
  int wave = tid >> 6, lane = tid & 63;
  int r = tid >> 1, kh = tid & 1;               // staging: row 0..127, k-half
  int mbase = (wave >> 1)*4;                    // wave's first mtile
  int nbase = (wave & 1)*4;                     // wave's first ntile

  const float* pa_base = tm  + ((size_t)b*T_ + r)*D_ + kh*16;
  const float* pb_base = sup + ((size_t)b*S_ + sbase + r)*D_ + kh*16;

  f32x4 acc[4][4];
  #pragma unroll
  for(int i=0;i<4;i++)
    #pragma unroll
    for(int j=0;j<4;j++) acc[i][j] = (f32x4){0.f,0.f,0.f,0.f};

  float nrm = 0.f;
  float4 a_reg[4], b_reg[4];
  #pragma unroll
  for(int it=0;it<4;it++){
    a_reg[it] = *(const float4*)(pa_base + it*4);
    b_reg[it] = *(const float4*)(pb_base + it*4);
  }

  for(int st=0; st<32; st++){
    __syncthreads();                            // LDS free (prev compute done)
    // convert + store hi/lo planes, accumulate sup row sumsq from fp32
    #pragma unroll
    for(int it=0;it<4;it++){
      float4 v = a_reg[it];
      int basei = ((r>>4)*2)*512 + ((kh*2+(it>>1))*16 + (r&15))*8 + (it&1)*4;
      unsigned short hx=bf16rn(v.x), hy=bf16rn(v.y), hz=bf16rn(v.z), hw=bf16rn(v.w);
      *(uint2*)&ldsA[basei] = make_uint2((unsigned)hx|((unsigned)hy<<16),(unsigned)hz|((unsigned)hw<<16));
      unsigned short lx=bf16rn(v.x-bf2f(hx)), ly=bf16rn(v.y-bf2f(hy)), lz=bf16rn(v.z-bf2f(hz)), lw=bf16rn(v.w-bf2f(hw));
      *(uint2*)&ldsA[basei + 512] = make_uint2((unsigned)lx|((unsigned)ly<<16),(unsigned)lz|((unsigned)lw<<16));

      float4 w = b_reg[it];
      nrm += w.x*w.x + w.y*w.y + w.z*w.z + w.w*w.w;
      unsigned short qx=bf16rn(w.x), qy=bf16rn(w.y), qz=bf16rn(w.z), qw=bf16rn(w.w);
      *(uint2*)&ldsB[basei] = make_uint2((unsigned)qx|((unsigned)qy<<16),(unsigned)qz|((unsigned)qw<<16));
      unsigned short ux=bf16rn(w.x-bf2f(qx)), uy=bf16rn(w.y-bf2f(qy)), uz=bf16rn(w.z-bf2f(qz)), uw=bf16rn(w.w-bf2f(qw));
      *(uint2*)&ldsB[basei + 512] = make_uint2((unsigned)ux|((unsigned)uy<<16),(unsigned)uz|((unsigned)uw<<16));
    }
    __syncthreads();
    if(st < 31){
      #pragma unroll
      for(int it=0;it<4;it++){
        a_reg[it] = *(const float4*)(pa_base + (st+1)*32 + it*4);
        b_reg[it] = *(const float4*)(pb_base + (st+1)*32 + it*4);
      }
    }
    short8 ah[4], al[4], bh[4], bl[4];
    #pragma unroll
    for(int i=0;i<4;i++){
      ah[i] = *(const short8*)&ldsA[((mbase+i)*2+0)*512 + lane*8];
      al[i] = *(const short8*)&ldsA[((mbase+i)*2+1)*512 + lane*8];
      bh[i] = *(const short8*)&ldsB[((nbase+i)*2+0)*512 + lane*8];
      bl[i] = *(const short8*)&ldsB[((nbase+i)*2+1)*512 + lane*8];
    }
    #pragma unroll
    for(int i=0;i<4;i++)
      #pragma unroll
      for(int j=0;j<4;j++){
        acc[i][j] = __builtin_amdgcn_mfma_f32_16x16x32_bf16(ah[i], bh[j], acc[i][j], 0,0,0);
        acc[i][j] = __builtin_amdgcn_mfma_f32_16x16x32_bf16(ah[i], bl[j], acc[i][j], 0,0,0);
        acc[i][j] = __builtin_amdgcn_mfma_f32_16x16x32_bf16(al[i], bh[j], acc[i][j], 0,0,0);
      }
  }

  // norms: pair-combine halves, publish to LDS
  float full = nrm + __shfl_xor(nrm, 1, 64);
  if(kh == 0) normB[r] = full;
  __syncthreads();

  // epilogue: per-row argmin of norm[s] - 2*dot; first-min tie-break via index compare
  int q = lane >> 4, c = lane & 15;
  #pragma unroll
  for(int mt=0; mt<4; mt++){
    #pragma unroll
    for(int i=0;i<4;i++){
      int t = (wave>>1)*64 + mt*16 + q*4 + i;
      float bv = BIGF; int bi = 0x7FFFFFFF;
      #pragma unroll
      for(int nt=0; nt<4; nt++){
        int sl = (wave&1)*64 + nt*16 + c;
        float sc = normB[sl] - 2.f*acc[mt][nt][i];
        int s = sbase + sl;
        if(sc < bv || (sc == bv && s < bi)){ bv = sc; bi = s; }
      }
      #pragma unroll
      for(int off=1; off<16; off<<=1){
        float ov = __shfl_xor(bv, off, 64);
        int   oi = __shfl_xor(bi, off, 64);
        if(ov < bv || (ov == bv && oi < bi)){ bv = ov; bi = oi; }
      }
      if(c == 0){
        pval[(size_t)(b*T_ + t)*PVW_ + ch*2 + (wave&1)] = bv;
        pidx[(size_t)(b*T_ + t)*PVW_ + ch*2 + (wave&1)] = bi;
      }
    }
  }
}

// ---------------- K5: final reduce + onehot + 0.5 * tm . proto^T ----------------
// grid B*16 (8 t per block), 256 thr: thread = (t_local = tid>>5, n = tid&31)
__global__ __launch_bounds__(256) void k_final(const float* __restrict__ tm, const float* __restrict__ pval,
        const int* __restrict__ pidx, const int* __restrict__ labels, const float* __restrict__ proto,
        float* __restrict__ out0){
  __shared__ int lbl_t[8];
  int b = blockIdx.x >> 4, tg = blockIdx.x & 15;
  int tid = threadIdx.x;
  if(tid < 8){
    int t = tg*8 + tid;
    float bv = BIGF; int bi = 0;
    #pragma unroll
    for(int c=0;c<PVW_;c++){
      float v = pval[(size_t)(b*T_ + t)*PVW_ + c];
      if(v < bv){ bv = v; bi = pidx[(size_t)(b*T_ + t)*PVW_ + c]; }
    }
    lbl_t[tid] = labels[b*S_ + bi];
  }
  __syncthreads();
  int tl = tid >> 5, n = tid & 31;
  int t = tg*8 + tl;
  const float4* tm4 = (const float4*)tm + (size_t)(b*T_ + t)*(D_/4);
  const float4* pr4 = (const float4*)proto + (size_t)(b*NT_ + n)*(D_/4);
  float acc = 0.f;
  #pragma unroll 8
  for(int d4=0; d4<D_/4; d4++){
    float4 x = tm4[d4], y = pr4[d4];
    acc += x.x*y.x + x.y*y.y + x.z*y.z + x.w*y.w;
  }
  out0[(size_t)(b*T_ + t)*NT_ + n] = 0.5f*acc + ((lbl_t[tl]==n) ? 1.f : 0.f);
}

extern "C" void kernel_launch(void* const* d_in, const int* in_sizes, int n_in,
                              void* d_out, int out_size, void* d_ws, size_t ws_size,
                              hipStream_t stream){
  const float* tr  = (const float*)d_in[0];   // test_reps    (B,K,T,D)
  const float* sup = (const float*)d_in[1];   // support_reps (B,K,L,D)
  const float* tgt = (const float*)d_in[4];   // support_targets (B,K,L,NT)
  float* out0  = (float*)d_out;                       // (B,T,NT)
  float* proto = out0 + (size_t)B_*T_*NT_;            // (B,NT,D)

  float* tm    = (float*)d_ws;                        // B*T*D
  int*   labels= (int*)(tm + (size_t)B_*T_*D_);       // B*S
  float* pval  = (float*)(labels + (size_t)B_*S_);    // B*T*PVW_
  int*   pidx  = (int*)(pval + (size_t)B_*T_*PVW_);   // B*T*PVW_

  k_mean<<<(B_*T_*(D_/4))/256, 256, 0, stream>>>(tr, tm);
  k_label<<<(B_*S_)/256, 256, 0, stream>>>(tgt, labels);
  k_proto<<<B_*8, 256, 0, stream>>>(sup, labels, proto);
  k_gemm_argmin<<<B_*NCH_, 256, 0, stream>>>(tm, sup, pval, pidx);
  k_final<<<B_*16, 256, 0, stream>>>(tm, pval, pidx, labels, proto, out0);
}